// Round 1
// baseline (341.142 us; speedup 1.0000x reference)
//
#include <hip/hip_runtime.h>

// Spiking NN collapses to 3 dependent masked binary matvecs (input drive is
// nonzero only at t=0; decaying membranes can never re-cross threshold):
//   enc = (u < x);  s0 = (W0*M0)@enc > 1;  s1 = (W1*M1)@s0 > 1;
//   out = ((W2*M2)@s1 > 1) ? 1/time_steps : 0
// HBM-bound: 384 MB streamed once. One wave per row, float4 loads, f64 acc
// (spike bit = strict >1.0 compare; one flip costs 1/128 >> 1.56e-4 threshold).

constexpr int N = 4096;

template <bool ENCODE, bool FINAL>
__global__ __launch_bounds__(256) void snn_layer(
    const float* __restrict__ W, const float* __restrict__ M,
    const float* __restrict__ S, const float* __restrict__ U,
    const int* __restrict__ t_steps, float* __restrict__ out)
{
    const int lane = threadIdx.x & 63;
    const int wave = threadIdx.x >> 6;
    const int row  = (blockIdx.x << 2) | wave;          // 4 rows per block

    const float4* W4 = reinterpret_cast<const float4*>(W + (size_t)row * N);
    const float4* M4 = reinterpret_cast<const float4*>(M + (size_t)row * N);
    const float4* S4 = reinterpret_cast<const float4*>(S);
    const float4* U4 = reinterpret_cast<const float4*>(U);

    double acc = 0.0;
#pragma unroll
    for (int it = 0; it < N / 4 / 64; ++it) {           // 16 iterations
        const int idx = it * 64 + lane;                 // coalesced: 1 KB/wave
        float4 w = W4[idx];
        float4 m = M4[idx];
        float4 s = S4[idx];
        if (ENCODE) {
            float4 uu = U4[idx];
            s.x = (uu.x < s.x) ? 1.0f : 0.0f;
            s.y = (uu.y < s.y) ? 1.0f : 0.0f;
            s.z = (uu.z < s.z) ? 1.0f : 0.0f;
            s.w = (uu.w < s.w) ? 1.0f : 0.0f;
        }
        // m and s are exact {0,1}; w*(m*s) is exact in f64 -> near-exact sum
        acc = fma((double)w.x, (double)(m.x * s.x), acc);
        acc = fma((double)w.y, (double)(m.y * s.y), acc);
        acc = fma((double)w.z, (double)(m.z * s.z), acc);
        acc = fma((double)w.w, (double)(m.w * s.w), acc);
    }

#pragma unroll
    for (int off = 32; off > 0; off >>= 1)
        acc += __shfl_down(acc, off, 64);

    if (lane == 0) {
        if (FINAL) {
            const float scale = 1.0f / (float)t_steps[0];
            out[row] = (acc > 1.0) ? scale : 0.0f;
        } else {
            out[row] = (acc > 1.0) ? 1.0f : 0.0f;
        }
    }
}

extern "C" void kernel_launch(void* const* d_in, const int* in_sizes, int n_in,
                              void* d_out, int out_size, void* d_ws, size_t ws_size,
                              hipStream_t stream)
{
    const float* x  = (const float*)d_in[0];
    const float* u  = (const float*)d_in[1];
    const float* W0 = (const float*)d_in[2];
    const float* W1 = (const float*)d_in[3];
    const float* W2 = (const float*)d_in[4];
    const float* M0 = (const float*)d_in[5];
    const float* M1 = (const float*)d_in[6];
    const float* M2 = (const float*)d_in[7];
    const int* t_steps = (const int*)d_in[8];
    float* out = (float*)d_out;

    float* s0 = (float*)d_ws;       // 4096 floats, fully rewritten each call
    float* s1 = s0 + N;             // 4096 floats

    dim3 grid(N / 4), block(256);
    snn_layer<true,  false><<<grid, block, 0, stream>>>(W0, M0, x,  u,       nullptr, s0);
    snn_layer<false, false><<<grid, block, 0, stream>>>(W1, M1, s0, nullptr, nullptr, s1);
    snn_layer<false, true ><<<grid, block, 0, stream>>>(W2, M2, s1, nullptr, t_steps, out);
}